// Round 1
// baseline (465.136 us; speedup 1.0000x reference)
//
#include <hip/hip_runtime.h>

typedef unsigned short u16;
typedef unsigned int   u32;
typedef __bf16 v8bf __attribute__((ext_vector_type(8)));
typedef float  v4f  __attribute__((ext_vector_type(4)));

#define INV_SQRT_W   0.044194173824159216f   // 1/sqrt(512)
#define INV_SQRT_KKC 0.029462782549439483f   // 1/sqrt(3*3*128)
#define LRELU_GAIN   1.4142135623730951f

__device__ __forceinline__ u16 f2bf(float f) {
    u32 u = __float_as_uint(f);
    u = (u + 0x7fffu + ((u >> 16) & 1u)) >> 16;   // RNE
    return (u16)u;
}

// ---------------- kernel A: s[n,i] and d[n,o] ----------------
__global__ void k_sd(const float* __restrict__ dlat,
                     const float* __restrict__ aw,
                     const float* __restrict__ ab,
                     const float* __restrict__ cw,
                     const int*   __restrict__ lidx,
                     float* __restrict__ s_out,
                     float* __restrict__ d_out)
{
    const int n = blockIdx.x;      // 8
    const int i = threadIdx.x;     // 128
    const int li = lidx[0];
    const float* z = dlat + (n * 16 + li) * 512;
    float a0 = 0.f, a1 = 0.f, a2 = 0.f, a3 = 0.f;
    for (int k = 0; k < 512; k += 4) {
        a0 += z[k + 0] * aw[(k + 0) * 128 + i];
        a1 += z[k + 1] * aw[(k + 1) * 128 + i];
        a2 += z[k + 2] * aw[(k + 2) * 128 + i];
        a3 += z[k + 3] * aw[(k + 3) * 128 + i];
    }
    float s = (a0 + a1 + a2 + a3) * INV_SQRT_W + ab[i];
    s_out[n * 128 + i] = s;
    __shared__ float s2[128];
    s2[i] = s * s;
    __syncthreads();
    float d0 = 0.f, d1 = 0.f;
    for (int t = 0; t < 9; ++t) {
        for (int ci = 0; ci < 128; ci += 2) {
            float w0 = cw[((t * 128 + ci) * 128) + i] * INV_SQRT_KKC;
            float w1 = cw[((t * 128 + ci + 1) * 128) + i] * INV_SQRT_KKC;
            d0 += w0 * w0 * s2[ci];
            d1 += w1 * w1 * s2[ci + 1];
        }
    }
    d_out[n * 128 + i] = 1.0f / sqrtf(d0 + d1 + 1e-8f);
}

// -------- kernel B: wmod[n][tap][o][i] = cw[tap][i][o]*inv*s[n,i]*d[n,o] (bf16) --------
__global__ void k_wmod(const float* __restrict__ cw,
                       const float* __restrict__ s_buf,
                       const float* __restrict__ d_buf,
                       u16* __restrict__ wmod)
{
    const int b   = blockIdx.x;          // n*9 + tap, 72 blocks
    const int n   = b / 9;
    const int tap = b - n * 9;
    const int tid = threadIdx.x;         // 256
    __shared__ float tile[128][129];
    for (int idx = tid; idx < 16384; idx += 256) {
        int i = idx >> 7, o = idx & 127;
        tile[i][o] = cw[(tap * 128 + i) * 128 + o];   // coalesced over o
    }
    __syncthreads();
    u16* wt = wmod + (b << 14);
    for (int idx = tid; idx < 16384; idx += 256) {
        int o = idx >> 7, i = idx & 127;
        float v = tile[i][o] * INV_SQRT_KKC * s_buf[n * 128 + i] * d_buf[n * 128 + o];
        wt[(o << 7) + i] = f2bf(v);                   // coalesced over i
    }
}

// ---------------- kernel C: implicit-GEMM 3x3 conv + epilogue ----------------
// block tile: 128 pixels (8 rows x 16 cols) x 128 cout, 4 waves (2x2), 16x16x32 bf16 MFMA
__global__ __launch_bounds__(256, 2) void k_conv(
    const float* __restrict__ x,
    const float* __restrict__ noise,
    const float* __restrict__ conv_b,
    const float* __restrict__ nstr,
    const u16*   __restrict__ wmod,
    float* __restrict__ out)
{
    __shared__ __align__(16) u16 xs[23040];    // [q=rr*18+cc][128 ci], XOR-swizzled
    __shared__ __align__(16) u16 wsh[16384];   // [o][128 i], XOR-swizzled

    const int bid = blockIdx.x;
    const int n   = bid >> 9;            // 8 n
    const int hb  = (bid >> 4) & 31;     // 32 h-blocks
    const int wb  = bid & 15;            // 16 w-blocks
    const int h0  = hb << 3, w0 = wb << 4;

    const int tid  = threadIdx.x;
    const int lane = tid & 63;
    const int wid  = tid >> 6;
    const int wm   = wid >> 1;           // wave row (0..1)
    const int wq   = wid & 1;            // wave col (0..1)
    const int lr   = lane & 15;
    const int kg   = lane >> 4;

    // ---- stage X halo tile (10 x 18 x 128) fp32 -> bf16, swizzled ----
    for (int t = tid; t < 2880; t += 256) {
        int q  = t >> 4, k8 = t & 15;
        int rr = q / 18, cc = q - rr * 18;
        int gh = h0 + rr - 1, gw = w0 + cc - 1;
        float v0 = 0.f, v1 = 0.f, v2 = 0.f, v3 = 0.f, v4 = 0.f, v5 = 0.f, v6 = 0.f, v7 = 0.f;
        if ((unsigned)gh < 256u && (unsigned)gw < 256u) {
            const float* src = x + (size_t)((((n << 8) + gh) << 8) + gw) * 128 + (k8 << 3);
            float4 fa = *(const float4*)(src);
            float4 fb = *(const float4*)(src + 4);
            v0 = fa.x; v1 = fa.y; v2 = fa.z; v3 = fa.w;
            v4 = fb.x; v5 = fb.y; v6 = fb.z; v7 = fb.w;
        }
        uint4 pk;
        pk.x = (u32)f2bf(v0) | ((u32)f2bf(v1) << 16);
        pk.y = (u32)f2bf(v2) | ((u32)f2bf(v3) << 16);
        pk.z = (u32)f2bf(v4) | ((u32)f2bf(v5) << 16);
        pk.w = (u32)f2bf(v6) | ((u32)f2bf(v7) << 16);
        int dst = (q << 7) + ((k8 << 3) ^ ((q & 7) << 3));
        *(uint4*)&xs[dst] = pk;
    }

    v4f acc[4][4];
    #pragma unroll
    for (int a = 0; a < 4; ++a)
        #pragma unroll
        for (int b2 = 0; b2 < 4; ++b2) {
            v4f zz = {0.f, 0.f, 0.f, 0.f};
            acc[a][b2] = zz;
        }

    __syncthreads();

    const u16* wbase = wmod + ((size_t)(n * 9) << 14);

    #pragma unroll 1
    for (int tap = 0; tap < 9; ++tap) {
        if (tap) __syncthreads();
        // ---- stage weights for this tap: 128 o x 128 i bf16, swizzled ----
        const u16* wg = wbase + (tap << 14);
        #pragma unroll
        for (int t = 0; t < 8; ++t) {
            int c  = tid + (t << 8);           // < 2048
            int o  = c >> 4, i8 = c & 15;
            uint4 val = *(const uint4*)(wg + (o << 7) + (i8 << 3));
            int dst = (o << 7) + ((i8 << 3) ^ ((o & 7) << 3));
            *(uint4*)&wsh[dst] = val;
        }
        __syncthreads();

        const int th = tap / 3, tw = tap - th * 3;
        #pragma unroll
        for (int kk = 0; kk < 4; ++kk) {
            v8bf af[4], bf_[4];
            const int xoff = (kk << 5) + (kg << 3);
            #pragma unroll
            for (int mi = 0; mi < 4; ++mi) {
                int q   = (wm * 4 + mi + th) * 18 + lr + tw;
                int idx = (q << 7) + (xoff ^ ((q & 7) << 3));
                af[mi] = *(const v8bf*)&xs[idx];
            }
            #pragma unroll
            for (int ni = 0; ni < 4; ++ni) {
                int o   = wq * 64 + ni * 16 + lr;
                int idx = (o << 7) + (xoff ^ ((o & 7) << 3));
                bf_[ni] = *(const v8bf*)&wsh[idx];
            }
            #pragma unroll
            for (int mi = 0; mi < 4; ++mi)
                #pragma unroll
                for (int ni = 0; ni < 4; ++ni)
                    acc[mi][ni] = __builtin_amdgcn_mfma_f32_16x16x32_bf16(
                        af[mi], bf_[ni], acc[mi][ni], 0, 0, 0);
        }
    }

    // ---- epilogue: + noise*strength + bias, lrelu * sqrt(2) ----
    const float ns = nstr[0];
    #pragma unroll
    for (int mi = 0; mi < 4; ++mi) {
        const int h = h0 + wm * 4 + mi;
        #pragma unroll
        for (int j = 0; j < 4; ++j) {
            const int w  = w0 + kg * 4 + j;
            const float nz = noise[((n << 8) + h) * 256 + w] * ns;
            float* orow = out + (size_t)((((n << 8) + h) << 8) + w) * 128;
            #pragma unroll
            for (int ni = 0; ni < 4; ++ni) {
                const int cout = wq * 64 + ni * 16 + lr;
                float v = acc[mi][ni][j] + nz + conv_b[cout];
                v = (v < 0.f ? 0.2f * v : v) * LRELU_GAIN;
                orow[cout] = v;
            }
        }
    }
}

extern "C" void kernel_launch(void* const* d_in, const int* in_sizes, int n_in,
                              void* d_out, int out_size, void* d_ws, size_t ws_size,
                              hipStream_t stream) {
    const float* x     = (const float*)d_in[0];
    const float* dlat  = (const float*)d_in[1];
    const float* noise = (const float*)d_in[2];
    const float* aw    = (const float*)d_in[3];
    const float* ab    = (const float*)d_in[4];
    const float* cw    = (const float*)d_in[5];
    const float* cb    = (const float*)d_in[6];
    const float* nstr  = (const float*)d_in[7];
    const int*   lidx  = (const int*)d_in[8];
    float* out = (float*)d_out;

    float* s_buf = (float*)d_ws;                          // 8*128 f32
    float* d_buf = s_buf + 1024;                          // 8*128 f32
    u16*   wmod  = (u16*)((char*)d_ws + 8192);            // 8*9*128*128 bf16 = 2.25 MiB

    k_sd  <<<8,    128, 0, stream>>>(dlat, aw, ab, cw, lidx, s_buf, d_buf);
    k_wmod<<<72,   256, 0, stream>>>(cw, s_buf, d_buf, wmod);
    k_conv<<<4096, 256, 0, stream>>>(x, noise, cb, nstr, wmod, out);
}

// Round 2
// 260.816 us; speedup vs baseline: 1.7834x; 1.7834x over previous
//
#include <hip/hip_runtime.h>

typedef unsigned short u16;
typedef unsigned int   u32;
typedef __bf16 v8bf __attribute__((ext_vector_type(8)));
typedef float  v4f  __attribute__((ext_vector_type(4)));

#define INV_SQRT_W   0.044194173824159216f   // 1/sqrt(512)
#define INV_SQRT_KKC 0.029462782549439483f   // 1/sqrt(3*3*128)
#define LRELU_GAIN   1.4142135623730951f

__device__ __forceinline__ u16 f2bf(float f) {
    u32 u = __float_as_uint(f);
    u = (u + 0x7fffu + ((u >> 16) & 1u)) >> 16;   // RNE
    return (u16)u;
}

__device__ __forceinline__ void glds16(const u16* g, u16* l) {
    __builtin_amdgcn_global_load_lds(
        (const __attribute__((address_space(1))) void*)g,
        (__attribute__((address_space(3))) void*)l, 16, 0, 0);
}

// ---------------- kernel S: s[n,i] = z @ (aw/sqrt(512)) + ab ----------------
__global__ void k_s(const float* __restrict__ dlat,
                    const float* __restrict__ aw,
                    const float* __restrict__ ab,
                    const int*   __restrict__ lidx,
                    float* __restrict__ s_out)
{
    const int n   = blockIdx.x;      // 8
    const int tid = threadIdx.x;     // 256
    const int i   = tid & 127, kh = tid >> 7;
    const int li  = lidx[0];
    const float* z = dlat + (n * 16 + li) * 512 + kh * 256;
    const float* a = aw + kh * 256 * 128 + i;
    float a0 = 0.f, a1 = 0.f, a2 = 0.f, a3 = 0.f;
    for (int k = 0; k < 256; k += 4) {
        a0 += z[k + 0] * a[(k + 0) * 128];
        a1 += z[k + 1] * a[(k + 1) * 128];
        a2 += z[k + 2] * a[(k + 2) * 128];
        a3 += z[k + 3] * a[(k + 3) * 128];
    }
    __shared__ float part[256];
    part[tid] = a0 + a1 + a2 + a3;
    __syncthreads();
    if (tid < 128)
        s_out[n * 128 + i] = (part[i] + part[i + 128]) * INV_SQRT_W + ab[i];
}

// ---------------- kernel W2: W2[i,o] = sum_t (cw[t,i,o]*inv)^2 ----------------
__global__ void k_w2(const float* __restrict__ cw, float* __restrict__ W2)
{
    const int idx = blockIdx.x * 256 + threadIdx.x;   // 16384 = i*128+o
    float acc = 0.f;
    #pragma unroll
    for (int t = 0; t < 9; ++t) {
        float w = cw[t * 16384 + idx];
        acc += w * w;
    }
    W2[idx] = acc * (INV_SQRT_KKC * INV_SQRT_KKC);
}

// ---------------- kernel D: d[n,o] = rsqrt(sum_i W2[i,o]*s2[n,i] + 1e-8) ----------------
__global__ void k_d(const float* __restrict__ W2,
                    const float* __restrict__ s_buf,
                    float* __restrict__ d_out)
{
    const int n = blockIdx.x;   // 8
    const int o = threadIdx.x;  // 128
    __shared__ float s2[128];
    float sv = s_buf[n * 128 + o];
    s2[o] = sv * sv;
    __syncthreads();
    float acc = 1e-8f;
    #pragma unroll 4
    for (int i = 0; i < 128; ++i)
        acc += W2[i * 128 + o] * s2[i];
    d_out[n * 128 + o] = 1.0f / sqrtf(acc);
}

// -------- kernel WMOD: pre-swizzled bf16 stage blocks for global_load_lds --------
// block b = n*18 + s, s = tap*2 + half. 16KB block = [o:128][i_local:64] bf16,
// element slot = (o<<6) + (i_local ^ ((o&7)<<3))  (XOR-swizzled, identity under glds)
__global__ void k_wmod(const float* __restrict__ cw,
                       const float* __restrict__ s_buf,
                       const float* __restrict__ d_buf,
                       u16* __restrict__ wmod)
{
    const int b    = blockIdx.x;         // 144
    const int n    = b / 18;
    const int s    = b - n * 18;
    const int tap  = s >> 1, half = s & 1;
    const int tid  = threadIdx.x;        // 256
    __shared__ float tile[64][132];
    __shared__ float dsh[128], ssh[64];
    const float* src = cw + (size_t)(tap * 128 + half * 64) * 128;
    for (int it = 0; it < 32; ++it) {
        int idx = it * 256 + tid;            // 8192
        tile[idx >> 7][idx & 127] = src[idx];
    }
    if (tid < 128) dsh[tid] = d_buf[n * 128 + tid];
    if (tid < 64)  ssh[tid] = s_buf[n * 128 + half * 64 + tid] * INV_SQRT_KKC;
    __syncthreads();
    u16* wt = wmod + ((size_t)b << 13);
    #pragma unroll
    for (int rep = 0; rep < 4; ++rep) {
        int chunk = rep * 256 + tid;         // 1024
        int o = chunk >> 3, i8 = chunk & 7;
        float dv = dsh[o];
        u32 pk[4];
        #pragma unroll
        for (int jj = 0; jj < 4; ++jj) {
            int il = i8 * 8 + jj * 2;
            float v0 = tile[il][o]     * ssh[il]     * dv;
            float v1 = tile[il + 1][o] * ssh[il + 1] * dv;
            pk[jj] = (u32)f2bf(v0) | ((u32)f2bf(v1) << 16);
        }
        int el = (o << 6) + ((i8 << 3) ^ ((o & 7) << 3));
        *(uint4*)&wt[el] = *(uint4*)pk;
    }
}

// ---------------- kernel CONV: implicit-GEMM 3x3 conv, 18-stage glds pipeline ----------------
__global__ __launch_bounds__(256, 2) void k_conv(
    const float* __restrict__ x,
    const float* __restrict__ noise,
    const float* __restrict__ conv_b,
    const float* __restrict__ nstr,
    const u16*   __restrict__ wmod,
    float* __restrict__ out)
{
    __shared__ __align__(16) u16 xs[23040];       // [q=rr*18+cc][128], XOR-swizzled
    __shared__ __align__(16) u16 wsh[2][8192];    // double-buffered 16KB weight stages

    const int bid0 = blockIdx.x;
    const int bid  = ((bid0 & 7) << 9) + (bid0 >> 3);   // XCD swizzle (4096%8==0, bijective)
    const int n   = bid >> 9;
    const int hb  = (bid >> 4) & 31;
    const int wb  = bid & 15;
    const int h0  = hb << 3, w0 = wb << 4;

    const int tid  = threadIdx.x;
    const int lane = tid & 63;
    const int wid  = tid >> 6;
    const int wm   = wid >> 1;
    const int wq   = wid & 1;
    const int lr   = lane & 15;
    const int kg   = lane >> 4;

    // ---- stage X halo tile (10 x 18 x 128) fp32 -> bf16, swizzled ----
    for (int t = tid; t < 2880; t += 256) {
        int q  = t >> 4, k8 = t & 15;
        int rr = q / 18, cc = q - rr * 18;
        int gh = h0 + rr - 1, gw = w0 + cc - 1;
        float v0 = 0.f, v1 = 0.f, v2 = 0.f, v3 = 0.f, v4 = 0.f, v5 = 0.f, v6 = 0.f, v7 = 0.f;
        if ((unsigned)gh < 256u && (unsigned)gw < 256u) {
            const float* src = x + (size_t)((((n << 8) + gh) << 8) + gw) * 128 + (k8 << 3);
            float4 fa = *(const float4*)(src);
            float4 fb = *(const float4*)(src + 4);
            v0 = fa.x; v1 = fa.y; v2 = fa.z; v3 = fa.w;
            v4 = fb.x; v5 = fb.y; v6 = fb.z; v7 = fb.w;
        }
        uint4 pk;
        pk.x = (u32)f2bf(v0) | ((u32)f2bf(v1) << 16);
        pk.y = (u32)f2bf(v2) | ((u32)f2bf(v3) << 16);
        pk.z = (u32)f2bf(v4) | ((u32)f2bf(v5) << 16);
        pk.w = (u32)f2bf(v6) | ((u32)f2bf(v7) << 16);
        int dst = (q << 7) + ((k8 << 3) ^ ((q & 7) << 3));
        *(uint4*)&xs[dst] = pk;
    }

    // ---- prologue: async-stage weight stage 0 into wsh[0] ----
    const u16* wn = wmod + ((size_t)(n * 18) << 13);
    #pragma unroll
    for (int t = 0; t < 4; ++t) {
        int chunk = (t << 2) + wid;
        glds16(wn + (chunk << 9) + (lane << 3), &wsh[0][chunk << 9]);
    }

    v4f acc[4][4];
    #pragma unroll
    for (int a = 0; a < 4; ++a)
        #pragma unroll
        for (int b2 = 0; b2 < 4; ++b2) {
            v4f zz = {0.f, 0.f, 0.f, 0.f};
            acc[a][b2] = zz;
        }

    __syncthreads();   // xs ready + wsh[0] landed (barrier drains vmcnt/lgkmcnt)

    #pragma unroll 1
    for (int s = 0; s < 18; ++s) {
        const int c = s & 1;
        if (s < 17) {   // prefetch next stage into the buffer freed at last barrier
            const u16* sb = wn + ((size_t)(s + 1) << 13);
            #pragma unroll
            for (int t = 0; t < 4; ++t) {
                int chunk = (t << 2) + wid;
                glds16(sb + (chunk << 9) + (lane << 3), &wsh[c ^ 1][chunk << 9]);
            }
        }
        const int tap = s >> 1;
        const int th = tap / 3, tw = tap - th * 3;
        const int hb64 = (s & 1) << 6;
        #pragma unroll
        for (int kk = 0; kk < 2; ++kk) {
            v8bf af[4], bf_[4];
            const int koff = (kk << 5) + (kg << 3);
            const int xoff = hb64 + koff;
            #pragma unroll
            for (int mi = 0; mi < 4; ++mi) {
                int q = (wm * 4 + mi + th) * 18 + lr + tw;
                af[mi] = *(const v8bf*)&xs[(q << 7) + (xoff ^ ((q & 7) << 3))];
            }
            #pragma unroll
            for (int ni = 0; ni < 4; ++ni) {
                int o = wq * 64 + ni * 16 + lr;
                bf_[ni] = *(const v8bf*)&wsh[c][(o << 6) + (koff ^ ((o & 7) << 3))];
            }
            #pragma unroll
            for (int mi = 0; mi < 4; ++mi)
                #pragma unroll
                for (int ni = 0; ni < 4; ++ni)
                    acc[mi][ni] = __builtin_amdgcn_mfma_f32_16x16x32_bf16(
                        af[mi], bf_[ni], acc[mi][ni], 0, 0, 0);
        }
        __syncthreads();   // waves done with wsh[c]; wsh[c^1] loads drained
    }

    // ---- epilogue: + noise*strength + bias, lrelu * sqrt(2) ----
    const float ns = nstr[0];
    #pragma unroll
    for (int mi = 0; mi < 4; ++mi) {
        const int h = h0 + wm * 4 + mi;
        #pragma unroll
        for (int j = 0; j < 4; ++j) {
            const int w  = w0 + kg * 4 + j;
            const float nz = noise[((n << 8) + h) * 256 + w] * ns;
            float* orow = out + (size_t)((((n << 8) + h) << 8) + w) * 128;
            #pragma unroll
            for (int ni = 0; ni < 4; ++ni) {
                const int cout = wq * 64 + ni * 16 + lr;
                float v = acc[mi][ni][j] + nz + conv_b[cout];
                v = (v < 0.f ? 0.2f * v : v) * LRELU_GAIN;
                orow[cout] = v;
            }
        }
    }
}

extern "C" void kernel_launch(void* const* d_in, const int* in_sizes, int n_in,
                              void* d_out, int out_size, void* d_ws, size_t ws_size,
                              hipStream_t stream) {
    const float* x     = (const float*)d_in[0];
    const float* dlat  = (const float*)d_in[1];
    const float* noise = (const float*)d_in[2];
    const float* aw    = (const float*)d_in[3];
    const float* ab    = (const float*)d_in[4];
    const float* cw    = (const float*)d_in[5];
    const float* cb    = (const float*)d_in[6];
    const float* nstr  = (const float*)d_in[7];
    const int*   lidx  = (const int*)d_in[8];
    float* out = (float*)d_out;

    float* s_buf = (float*)d_ws;                               // 4KB
    float* d_buf = (float*)((char*)d_ws + 4096);               // 4KB
    // W2 (64KB) aliases the wmod region: k_d finishes before k_wmod writes (stream order)
    float* W2    = (float*)((char*)d_ws + 8192);
    u16*   wmod  = (u16*)((char*)d_ws + 8192);                 // 8*18*8192*2B = 2.25MB

    k_w2  <<<64,  256, 0, stream>>>(cw, W2);
    k_s   <<<8,   256, 0, stream>>>(dlat, aw, ab, lidx, s_buf);
    k_d   <<<8,   128, 0, stream>>>(W2, s_buf, d_buf);
    k_wmod<<<144, 256, 0, stream>>>(cw, s_buf, d_buf, wmod);
    k_conv<<<4096,256, 0, stream>>>(x, noise, cb, nstr, wmod, out);
}